// Round 1
// baseline (997.652 us; speedup 1.0000x reference)
//
#include <hip/hip_runtime.h>

#define N_NODES 2048
#define N_EDGES 65536
#define D       64
#define GAT_EPS 1e-6f

typedef unsigned int u32;

// ---------------------------------------------------------------------------
// K1: fused front end.
//   blocks [0,512):   P[n][d]  = x[n]·Wf[:64,d],  Qb[n][d] = x[n]·Wf[64:,d]+bf[d]
//   blocks [512,520): u[n] = x[n]·Ww[:64], vb[n] = x[n]·Ww[64:]+bw, cnt[n]=0
//   blocks [520,4616): stream the two 512MB one-hot matrices -> sidx/tidx.
// The 520 node-projection blocks are scheduled first and finish entirely
// under the BW-bound scan (~170us). No dependencies inside the kernel.
// ---------------------------------------------------------------------------
__global__ void __launch_bounds__(256) k_front(
        const uint4* __restrict__ src, const uint4* __restrict__ tgt,
        const float* __restrict__ x,
        const float* __restrict__ Wf, const float* __restrict__ bf,
        const float* __restrict__ Ww, const float* __restrict__ bw,
        float* __restrict__ P, float* __restrict__ Qb,
        float* __restrict__ u, float* __restrict__ vb,
        int* __restrict__ cnt,
        int* __restrict__ sidx, int* __restrict__ tidx) {
    u32 b = blockIdx.x, tid = threadIdx.x;
    if (b < 512u) {
        u32 i = b * 256u + tid;                 // [0, 131072)
        u32 n = i >> 6, d = i & 63u;
        const float* xr = x + n * 64u;
        float accP = 0.f, accQ = bf[d];
        #pragma unroll
        for (int k = 0; k < 64; ++k) {
            float xv = xr[k];                   // wave-uniform broadcast
            accP = fmaf(xv, Wf[k * 64 + d], accP);          // coalesced
            accQ = fmaf(xv, Wf[(k + 64) * 64 + d], accQ);
        }
        P[i] = accP; Qb[i] = accQ;
        return;
    }
    if (b < 520u) {
        u32 n = (b - 512u) * 256u + tid;        // [0, 2048)
        const float* xr = x + n * 64u;
        float au = 0.f, av = bw[0];
        #pragma unroll
        for (int k = 0; k < 64; ++k) {
            float xv = xr[k];
            au = fmaf(xv, Ww[k], au);
            av = fmaf(xv, Ww[64 + k], av);
        }
        u[n] = au; vb[n] = av; cnt[n] = 0;
        return;
    }
    // ---- one-hot index extraction: 64 grid-strided uint4 loads/thread ----
    u32 eb = b - 520u;
    const uint4* m; int* idx;
    if (eb < 2048u) { m = src; idx = sidx; }
    else            { m = tgt; idx = tidx; eb -= 2048u; }
    u32 t0 = eb * 256u + tid;
    const u32 S = 524288u;                      // grid stride in uint4
    #pragma unroll 4
    for (u32 it = 0; it < 64u; ++it) {
        u32 t = t0 + it * S;                    // < N*E/4 = 33554432
        uint4 v = m[t];
        if (v.x | v.y | v.z | v.w) {
            u32 elem = t * 4u;                  // flat n*65536 + e
            int n = (int)(elem >> 16);
            int e = (int)(elem & 65535u);
            if (v.x) idx[e]     = n;
            if (v.y) idx[e + 1] = n;
            if (v.z) idx[e + 2] = n;
            if (v.w) idx[e + 3] = n;
        }
    }
}

// ---------------------------------------------------------------------------
// K2: per-target-node degree histogram (65536 atomics over 2048 counters).
// ---------------------------------------------------------------------------
__global__ void __launch_bounds__(256) k_count(const int* __restrict__ tidx,
                                               int* __restrict__ cnt) {
    int e = blockIdx.x * 256 + threadIdx.x;
    atomicAdd(&cnt[tidx[e] & (N_NODES - 1)], 1);
}

// ---------------------------------------------------------------------------
// K3: single-block exclusive scan of cnt[2048] -> row_start[2049], cursor.
// ---------------------------------------------------------------------------
__global__ void __launch_bounds__(256) k_scan(const int* __restrict__ cnt,
                                              int* __restrict__ row_start,
                                              int* __restrict__ cursor) {
    __shared__ int part[256];
    int t = threadIdx.x;
    int c[8]; int s = 0;
    #pragma unroll
    for (int j = 0; j < 8; ++j) { c[j] = cnt[t * 8 + j]; s += c[j]; }
    part[t] = s;
    __syncthreads();
    for (int off = 1; off < 256; off <<= 1) {   // Hillis-Steele inclusive
        int v = (t >= off) ? part[t - off] : 0;
        __syncthreads();
        part[t] += v;
        __syncthreads();
    }
    int base = (t == 0) ? 0 : part[t - 1];      // exclusive prefix
    #pragma unroll
    for (int j = 0; j < 8; ++j) {
        row_start[t * 8 + j] = base;
        cursor[t * 8 + j]    = base;
        base += c[j];
    }
    if (t == 255) row_start[2048] = base;       // = 65536
}

// ---------------------------------------------------------------------------
// K4: bucket edge ids by target node (CSR fill).
// ---------------------------------------------------------------------------
__global__ void __launch_bounds__(256) k_bucket(const int* __restrict__ tidx,
                                                int* __restrict__ cursor,
                                                int* __restrict__ csr) {
    int e = blockIdx.x * 256 + threadIdx.x;
    int t = tidx[e] & (N_NODES - 1);
    int p = atomicAdd(&cursor[t], 1);
    csr[p & (N_EDGES - 1)] = e;
}

// ---------------------------------------------------------------------------
// K5: one wave per target node, lane = output dim. Atomic-free reduction:
//   a_e  = exp(u[s_e] + v[n] + bw)        (one exp per edge, lane-parallel)
//   o[n] = sum_e a_e * relu(P[s_e] + Qb[n]) / (sum_e a_e + eps)
// Softmax mean-shift dropped: cancels exactly in the ratio up to eps*exp(m),
// a ~1e-8 relative perturbation (same as the previously-passing kernel).
// ---------------------------------------------------------------------------
__global__ void __launch_bounds__(256) k_out(
        const float* __restrict__ P, const float* __restrict__ Qb,
        const float* __restrict__ u, const float* __restrict__ vb,
        const int* __restrict__ sidx, const int* __restrict__ row_start,
        const int* __restrict__ csr, float* __restrict__ out) {
    int tid  = threadIdx.x;
    int lane = tid & 63;
    int n    = blockIdx.x * 4 + (tid >> 6);
    int start = row_start[n], end = row_start[n + 1];
    float qd = Qb[n * 64 + lane];
    float vn = vb[n];
    float acc = 0.f, asum = 0.f;
    for (int base = start; base < end; base += 64) {
        int m = end - base;
        float a_l = 0.f; int s_l = 0;
        if (lane < m) {                          // cooperative edge preload
            int e = csr[base + lane] & (N_EDGES - 1);
            s_l = sidx[e] & (N_NODES - 1);
            a_l = __expf(u[s_l] + vn);
        }
        int c = m < 64 ? m : 64;
        int j = 0;
        for (; j + 4 <= c; j += 4) {             // 4 P-rows in flight
            int   s0 = __shfl(s_l, j),     s1 = __shfl(s_l, j + 1);
            int   s2 = __shfl(s_l, j + 2), s3 = __shfl(s_l, j + 3);
            float a0 = __shfl(a_l, j),     a1 = __shfl(a_l, j + 1);
            float a2 = __shfl(a_l, j + 2), a3 = __shfl(a_l, j + 3);
            float y0 = P[s0 * 64 + lane] + qd;
            float y1 = P[s1 * 64 + lane] + qd;
            float y2 = P[s2 * 64 + lane] + qd;
            float y3 = P[s3 * 64 + lane] + qd;
            asum += (a0 + a1) + (a2 + a3);
            acc = fmaf(a0, fmaxf(y0, 0.f), acc);
            acc = fmaf(a1, fmaxf(y1, 0.f), acc);
            acc = fmaf(a2, fmaxf(y2, 0.f), acc);
            acc = fmaf(a3, fmaxf(y3, 0.f), acc);
        }
        for (; j < c; ++j) {
            int   s = __shfl(s_l, j);
            float a = __shfl(a_l, j);
            float y = P[s * 64 + lane] + qd;
            asum += a;
            acc = fmaf(a, fmaxf(y, 0.f), acc);
        }
    }
    out[n * 64 + lane] = acc / (asum + GAT_EPS);
}

extern "C" void kernel_launch(void* const* d_in, const int* in_sizes, int n_in,
                              void* d_out, int out_size, void* d_ws, size_t ws_size,
                              hipStream_t stream) {
    const float* x   = (const float*)d_in[0];
    const float* src = (const float*)d_in[1];
    const float* tgt = (const float*)d_in[2];
    const float* Wf  = (const float*)d_in[3];
    const float* bf  = (const float*)d_in[4];
    const float* Ww  = (const float*)d_in[5];
    const float* bw  = (const float*)d_in[6];
    float* out = (float*)d_out;

    char* ws = (char*)d_ws;
    // ws layout (bytes):
    //   P        0       .. 524288    (2048*64 f32)
    //   Qb       524288  .. 1048576   (2048*64 f32, bf folded in)
    //   u        1048576 .. 1056768   (2048 f32)
    //   vb       1056768 .. 1064960   (2048 f32, bw folded in)
    //   cnt      1064960 .. 1073152   (2048 i32)
    //   row_s    1073152 .. 1081600   (2049 i32 + pad)
    //   cursor   1081600 .. 1089792   (2048 i32)
    //   sidx     1089792 .. 1351936   (65536 i32)
    //   tidx     1351936 .. 1614080   (65536 i32)
    //   csr      1614080 .. 1876224   (65536 i32)
    float* P     = (float*)(ws);
    float* Qb    = (float*)(ws + 524288);
    float* u     = (float*)(ws + 1048576);
    float* vb    = (float*)(ws + 1056768);
    int*   cnt   = (int*)  (ws + 1064960);
    int*   row_s = (int*)  (ws + 1073152);
    int*   curs  = (int*)  (ws + 1081600);
    int*   sidx  = (int*)  (ws + 1089792);
    int*   tidx  = (int*)  (ws + 1351936);
    int*   csr   = (int*)  (ws + 1614080);

    k_front<<<4616, 256, 0, stream>>>((const uint4*)src, (const uint4*)tgt, x,
                                      Wf, bf, Ww, bw, P, Qb, u, vb, cnt,
                                      sidx, tidx);
    k_count<<<N_EDGES / 256, 256, 0, stream>>>(tidx, cnt);
    k_scan<<<1, 256, 0, stream>>>(cnt, row_s, curs);
    k_bucket<<<N_EDGES / 256, 256, 0, stream>>>(tidx, curs, csr);
    k_out<<<N_NODES / 4, 256, 0, stream>>>(P, Qb, u, vb, sidx, row_s, csr, out);
}